// Round 3
// baseline (157.642 us; speedup 1.0000x reference)
//
#include <hip/hip_runtime.h>
#include <stdint.h>

typedef short s16x8 __attribute__((ext_vector_type(8)));
typedef unsigned short u16x8 __attribute__((ext_vector_type(8)));
typedef float f32x4 __attribute__((ext_vector_type(4)));

#define XPAD_ELEMS (32 * 58 * 58 * 128)
#define XPAD_BYTES ((size_t)XPAD_ELEMS * 2)
#define WQ_BYTES ((size_t)9 * 256 * 128 * 2)

static __device__ __forceinline__ unsigned short f2bf(float f) {
    union { float f; uint32_t u; } v; v.f = f;
    uint32_t r = v.u + 0x7FFFu + ((v.u >> 16) & 1u);
    return (unsigned short)(r >> 16);
}

static __device__ __forceinline__ s16x8 ldfrag(const unsigned short* p) {
    return *(const s16x8*)p;
}

// async 16B global -> LDS (linear: wave-uniform LDS base + lane*16)
static __device__ __forceinline__ void gload16(const unsigned short* g, unsigned short* l) {
    __builtin_amdgcn_global_load_lds(
        (const __attribute__((address_space(1))) uint32_t*)g,
        (__attribute__((address_space(3))) uint32_t*)l, 16, 0, 0);
}

// ---------------- weight quantization ----------------
__global__ void quant_k(const float* __restrict__ pc,
                        const float* __restrict__ ql,
                        unsigned short* __restrict__ wq) {
    int p = blockIdx.x * 256 + threadIdx.x;
    if (p >= 9 * 256 * 128) return;
    int c = p & 127;
    int o = (p >> 7) & 255;
    int kpos = p >> 15;
    const float* v = pc + ((size_t)((o * 128 + c) * 9 + kpos) * 7);
    float vv[7];
    float s = 0.f;
#pragma unroll
    for (int j = 0; j < 7; ++j) { vv[j] = v[j]; s += vv[j] * vv[j]; }
    float norm = sqrtf(s);
    float best = 10.0f * (vv[0] / norm);
    int bi = 0;
#pragma unroll
    for (int j = 1; j < 7; ++j) {
        float t = 10.0f * (vv[j] / norm);
        if (t > best) { best = t; bi = j; }
    }
    wq[p] = f2bf(ql[bi]);
}

// ---------------- zero only the halo border of xpad ----------------
// A: rows {0,57}: 32*2*58*16 vec8 = 59392 ; B: cols {0,57} rows 1..56: 32*56*2*16 = 57344
__global__ void border_k(unsigned short* __restrict__ xpad) {
    int i = blockIdx.x * 256 + threadIdx.x;
    const u16x8 z = (u16x8){0, 0, 0, 0, 0, 0, 0, 0};
    if (i < 59392) {
        int cseg = i & 15;
        int pos = (i >> 4) % 58;
        int t = (i >> 4) / 58;
        int r = (t & 1) * 57;
        int n = t >> 1;
        *(u16x8*)(xpad + ((size_t)(n * 58 + r) * 58 + pos) * 128 + cseg * 8) = z;
    } else {
        int j = i - 59392;
        if (j < 57344) {
            int cseg = j & 15;
            int t = j >> 4;
            int col = (t & 1) * 57;
            int hh = (t >> 1) % 56;
            int n = (t >> 1) / 56;
            *(u16x8*)(xpad + ((size_t)(n * 58 + hh + 1) * 58 + col) * 128 + cseg * 8) = z;
        }
    }
}

// ---------------- x: NCHW f32 -> padded NHWC bf16 (interior) ----------------
__global__ __launch_bounds__(256) void xform_k(const float* __restrict__ x,
                                               unsigned short* __restrict__ xpad) {
    __shared__ float tile[64 * 57];
    const int h = blockIdx.x;
    const int n = blockIdx.y;
    const int c0 = blockIdx.z * 64;
    const int t = threadIdx.x;
    if (t < 224) {
        int c4 = t / 56;
        int w = t - c4 * 56;
        const float* src = x + ((size_t)(n * 128 + c0 + c4) * 56 + h) * 56 + w;
#pragma unroll
        for (int cc = 0; cc < 16; ++cc)
            tile[(cc * 4 + c4) * 57 + w] = src[(size_t)cc * 4 * 3136];
    }
    __syncthreads();
    int c = t & 63, wg = t >> 6;
    unsigned short* dst = xpad + ((size_t)(n * 58 + h + 1) * 58 + 1) * 128 + c0 + c;
#pragma unroll
    for (int ww = 0; ww < 14; ++ww) {
        int w = ww * 4 + wg;
        dst[(size_t)w * 128] = f2bf(tile[c * 57 + w]);
    }
}

// ---------------- implicit-GEMM conv, 64o x 112s per wave ----------------
// xpad: [32][58][58][128] bf16, wq: [9][256][128] bf16, out: [32][256][56][56] f32
// Block: 64 o x (8 rows x 56), 4 waves each 64o x 112s (rows 2w..2w+1).
// LDS xs: [cseg 0..3][pos 0..639(580 used)] 16B chunks ; wl: [cseg][kk*64+o] 16B.
__global__ __launch_bounds__(256) void conv3_k(const unsigned short* __restrict__ xpad,
                                               const unsigned short* __restrict__ wq,
                                               float* __restrict__ out) {
    __shared__ __align__(16) unsigned short xs[2560 * 8];   // 40960 B
    __shared__ __align__(16) unsigned short wl[2304 * 8];   // 36864 B

    const int tid = threadIdx.x;
    const int h0 = blockIdx.x * 8;
    const int n = blockIdx.y;
    const int o0 = blockIdx.z * 64;
    const int lane = tid & 63;
    const int wave = tid >> 6;
    const int l16 = lane & 15;
    const int kgrp = lane >> 4;

    // ---- staging source offsets (c0-independent part) ----
    int offx[10];
#pragma unroll
    for (int i = 0; i < 10; ++i) {
        int ci = i * 256 + tid;          // 0..2559
        int cseg = ci / 640;
        int pos = ci - cseg * 640;
        int pe = pos < 580 ? pos : 579;  // clamp pads to a valid address
        int r = pe / 58;
        int col = pe - r * 58;
        offx[i] = ((n * 58 + h0 + r) * 58 + col) * 128 + cseg * 8;
    }
    int offw[9];
#pragma unroll
    for (int i = 0; i < 9; ++i) {
        int ci = i * 256 + tid;          // 0..2303
        int cseg = ci / 576;
        int rem = ci - cseg * 576;
        int kk = rem >> 6;
        int o = rem & 63;
        offw[i] = (kk * 256 + o0 + o) * 128 + cseg * 8;
    }

    // ---- MFMA fragment bases ----
    int rr[7], wwv[7], bb[7];
#pragma unroll
    for (int f = 0; f < 7; ++f) {
        int s = wave * 112 + f * 16 + l16;   // 0..447
        int r = s / 56;
        int w = s - r * 56;
        rr[f] = r; wwv[f] = w;
        bb[f] = (kgrp * 640 + r * 58 + w) * 8;
    }
    const int ab = (kgrp * 576 + l16) * 8;

    f32x4 acc[4][7];
#pragma unroll
    for (int a = 0; a < 4; ++a)
#pragma unroll
        for (int f = 0; f < 7; ++f) acc[a][f] = (f32x4){0.f, 0.f, 0.f, 0.f};

    for (int c0 = 0; c0 < 128; c0 += 32) {
#pragma unroll
        for (int i = 0; i < 10; ++i)
            gload16(xpad + offx[i] + c0, &xs[(i * 256 + wave * 64) * 8]);
#pragma unroll
        for (int i = 0; i < 9; ++i)
            gload16(wq + offw[i] + c0, &wl[(i * 256 + wave * 64) * 8]);
        __syncthreads();

#pragma unroll
        for (int kk = 0; kk < 9; ++kk) {
            const int kh = kk / 3;
            const int kw = kk - kh * 3;
            s16x8 a0 = ldfrag(&wl[ab + kk * 512]);
            s16x8 a1 = ldfrag(&wl[ab + kk * 512 + 128]);
            s16x8 a2 = ldfrag(&wl[ab + kk * 512 + 256]);
            s16x8 a3 = ldfrag(&wl[ab + kk * 512 + 384]);
            const int xo = (kh * 58 + kw) * 8;
#pragma unroll
            for (int f = 0; f < 7; ++f) {
                s16x8 b = ldfrag(&xs[bb[f] + xo]);
                acc[0][f] = __builtin_amdgcn_mfma_f32_16x16x32_bf16(a0, b, acc[0][f], 0, 0, 0);
                acc[1][f] = __builtin_amdgcn_mfma_f32_16x16x32_bf16(a1, b, acc[1][f], 0, 0, 0);
                acc[2][f] = __builtin_amdgcn_mfma_f32_16x16x32_bf16(a2, b, acc[2][f], 0, 0, 0);
                acc[3][f] = __builtin_amdgcn_mfma_f32_16x16x32_bf16(a3, b, acc[3][f], 0, 0, 0);
            }
        }
        __syncthreads();
    }

    // ---- epilogue ----
#pragma unroll
    for (int of = 0; of < 4; ++of) {
        int ob = o0 + of * 16 + kgrp * 4;
#pragma unroll
        for (int f = 0; f < 7; ++f) {
            int h = h0 + rr[f];
            float* dst = out + ((size_t)(n * 256 + ob) * 56 + h) * 56 + wwv[f];
#pragma unroll
            for (int j = 0; j < 4; ++j) dst[(size_t)j * 3136] = acc[of][f][j];
        }
    }
}

// ---------------- fallback conv (round-1 verified) ----------------
__global__ __launch_bounds__(256) void conv_fb_k(const float* __restrict__ x,
                                                 const unsigned short* __restrict__ wq,
                                                 float* __restrict__ out) {
    __shared__ __align__(16) unsigned short xsf[6 * 58 * 40];
    __shared__ __align__(16) unsigned short wlf[9 * 64 * 40];

    const int tid = threadIdx.x;
    const int h0 = blockIdx.x * 4;
    const int n = blockIdx.y;
    const int o0 = blockIdx.z * 64;
    const int lane = tid & 63;
    const int wave = tid >> 6;
    const int wo = wave >> 1;
    const int wsd = wave & 1;
    const int l16 = lane & 15;
    const int kgrp = lane >> 4;

    int xb[7]; int rr[7]; int wwv[7];
#pragma unroll
    for (int f = 0; f < 7; ++f) {
        int s = wsd * 112 + f * 16 + l16;
        int r = s / 56;
        int w = s - r * 56;
        rr[f] = r; wwv[f] = w;
        xb[f] = (r * 58 + w) * 40 + kgrp * 8;
    }
    const int wa = (wo * 32 + l16) * 40 + kgrp * 8;

    f32x4 acc[2][7];
#pragma unroll
    for (int a = 0; a < 2; ++a)
#pragma unroll
        for (int f = 0; f < 7; ++f) acc[a][f] = (f32x4){0.f, 0.f, 0.f, 0.f};

    for (int c0 = 0; c0 < 128; c0 += 32) {
        for (int e = tid; e < 32 * 6 * 58; e += 256) {
            int c = e / 348;
            int rem = e - c * 348;
            int r = rem / 58;
            int col = rem - r * 58;
            int h = h0 - 1 + r;
            int w = col - 1;
            float val = 0.f;
            if ((unsigned)h < 56u && (unsigned)w < 56u)
                val = x[((size_t)(n * 128 + c0 + c) * 56 + h) * 56 + w];
            xsf[(r * 58 + col) * 40 + c] = f2bf(val);
        }
#pragma unroll
        for (int it = 0; it < 9; ++it) {
            int v = tid + it * 256;
            int cseg = v & 3;
            int o = (v >> 2) & 63;
            int kk = v >> 8;
            u16x8 dat = *(const u16x8*)(wq + (size_t)(kk * 256 + o0 + o) * 128 + c0 + cseg * 8);
            *(u16x8*)(&wlf[(kk * 64 + o) * 40 + cseg * 8]) = dat;
        }
        __syncthreads();
#pragma unroll
        for (int kk = 0; kk < 9; ++kk) {
            const int kh = kk / 3;
            const int kw = kk - kh * 3;
            s16x8 a0 = ldfrag(&wlf[kk * 2560 + wa]);
            s16x8 a1 = ldfrag(&wlf[kk * 2560 + wa + 640]);
            const int xoff = (kh * 58 + kw) * 40;
#pragma unroll
            for (int f = 0; f < 7; ++f) {
                s16x8 b = ldfrag(&xsf[xb[f] + xoff]);
                acc[0][f] = __builtin_amdgcn_mfma_f32_16x16x32_bf16(a0, b, acc[0][f], 0, 0, 0);
                acc[1][f] = __builtin_amdgcn_mfma_f32_16x16x32_bf16(a1, b, acc[1][f], 0, 0, 0);
            }
        }
        __syncthreads();
    }

#pragma unroll
    for (int of = 0; of < 2; ++of) {
        int ob = o0 + wo * 32 + of * 16 + kgrp * 4;
#pragma unroll
        for (int f = 0; f < 7; ++f) {
            int h = h0 + rr[f];
            float* dst = out + ((size_t)(n * 256 + ob) * 56 + h) * 56 + wwv[f];
#pragma unroll
            for (int j = 0; j < 4; ++j) dst[(size_t)j * 3136] = acc[of][f][j];
        }
    }
}

extern "C" void kernel_launch(void* const* d_in, const int* in_sizes, int n_in,
                              void* d_out, int out_size, void* d_ws, size_t ws_size,
                              hipStream_t stream) {
    const float* x = (const float*)d_in[0];
    const float* pc = (const float*)d_in[1];
    const float* ql = (const float*)d_in[2];
    float* out = (float*)d_out;

    if (ws_size >= XPAD_BYTES + WQ_BYTES) {
        unsigned short* xpad = (unsigned short*)d_ws;
        unsigned short* wq = (unsigned short*)((char*)d_ws + XPAD_BYTES);
        border_k<<<456, 256, 0, stream>>>(xpad);
        quant_k<<<1152, 256, 0, stream>>>(pc, ql, wq);
        xform_k<<<dim3(56, 32, 2), 256, 0, stream>>>(x, xpad);
        conv3_k<<<dim3(7, 32, 4), 256, 0, stream>>>(xpad, wq, out);
    } else {
        unsigned short* wq = (unsigned short*)d_ws;
        quant_k<<<1152, 256, 0, stream>>>(pc, ql, wq);
        conv_fb_k<<<dim3(14, 32, 4), 256, 0, stream>>>(x, wq, out);
    }
}

// Round 4
// 115.394 us; speedup vs baseline: 1.3661x; 1.3661x over previous
//
#include <hip/hip_runtime.h>
#include <stdint.h>

typedef short s16x8 __attribute__((ext_vector_type(8)));
typedef unsigned short u16x8 __attribute__((ext_vector_type(8)));
typedef float f32x4 __attribute__((ext_vector_type(4)));

#define XPAD_ELEMS (32 * 58 * 58 * 128)
#define XPAD_BYTES ((size_t)XPAD_ELEMS * 2)
#define WQ_BYTES ((size_t)9 * 16 * 256 * 8 * 2)

// xpad layout: [n][row 0..57][cseg 0..15][col 0..57][8c]  (16B chunk = 8 c's)
// wq   layout: [kk 0..8][cseg 0..15][o 0..255][8c]

static __device__ __forceinline__ unsigned short f2bf(float f) {
    union { float f; uint32_t u; } v; v.f = f;
    uint32_t r = v.u + 0x7FFFu + ((v.u >> 16) & 1u);
    return (unsigned short)(r >> 16);
}

static __device__ __forceinline__ s16x8 ldfrag(const unsigned short* p) {
    return *(const s16x8*)p;
}

// async 16B global -> LDS (wave-uniform LDS base + lane*16)
static __device__ __forceinline__ void gload16(const unsigned short* g, unsigned short* l) {
    __builtin_amdgcn_global_load_lds(
        (const __attribute__((address_space(1))) uint32_t*)g,
        (__attribute__((address_space(3))) uint32_t*)l, 16, 0, 0);
}

// ---------------- weight quantization -> [kk][cseg][o][8] ----------------
__global__ void quant_k(const float* __restrict__ pc,
                        const float* __restrict__ ql,
                        unsigned short* __restrict__ wq) {
    int p = blockIdx.x * 256 + threadIdx.x;   // output-order index
    if (p >= 9 * 16 * 256 * 8) return;
    int j = p & 7;
    int o = (p >> 3) & 255;
    int cs = (p >> 11) & 15;
    int kk = p >> 15;
    int c = cs * 8 + j;
    const float* v = pc + ((size_t)((o * 128 + c) * 9 + kk) * 7);
    float vv[7];
    float s = 0.f;
#pragma unroll
    for (int l = 0; l < 7; ++l) { vv[l] = v[l]; s += vv[l] * vv[l]; }
    float norm = sqrtf(s);
    float best = 10.0f * (vv[0] / norm);
    int bi = 0;
#pragma unroll
    for (int l = 1; l < 7; ++l) {
        float t = 10.0f * (vv[l] / norm);
        if (t > best) { best = t; bi = l; }
    }
    wq[p] = f2bf(ql[bi]);
}

// ---------------- zero the halo border of xpad ----------------
// per n: rows {0,57} all cols (2*16*58=1856 chunks) + cols {0,57} rows 1..56 (2*16*56=1792)
__global__ void border_k(unsigned short* __restrict__ xpad) {
    int i = blockIdx.x * 256 + threadIdx.x;   // 456*256 = 116736 = 32*3648
    const u16x8 z = (u16x8){0, 0, 0, 0, 0, 0, 0, 0};
    int n = i / 3648;
    int rem = i - n * 3648;
    int r, cs, col;
    if (rem < 1856) {
        int rt = rem / 928;          // 0,1
        int q = rem - rt * 928;
        r = rt * 57;
        cs = q / 58;
        col = q - cs * 58;
    } else {
        int rem2 = rem - 1856;
        int ct = rem2 / 896;         // 0,1
        int q = rem2 - ct * 896;
        col = ct * 57;
        cs = q / 56;
        r = 1 + (q - cs * 56);
    }
    *(u16x8*)(xpad + ((((size_t)n * 58 + r) * 16 + cs) * 58 + col) * 8) = z;
}

// ---------------- x: NCHW f32 -> padded [n][row][cseg][col][8] bf16 ----------------
__global__ __launch_bounds__(256) void xform_k(const float* __restrict__ x,
                                               unsigned short* __restrict__ xpad) {
    const int h = blockIdx.x;      // 0..55
    const int n = blockIdx.y;
    const int t = threadIdx.x;
    if (t >= 224) return;
    int cgrp = t / 56;             // 0..3
    int w = t - cgrp * 56;
#pragma unroll
    for (int seg = 0; seg < 4; ++seg) {
        int cs = seg * 4 + cgrp;   // 0..15
        const float* src = x + ((size_t)(n * 128 + cs * 8) * 56 + h) * 56 + w;
        u16x8 d;
#pragma unroll
        for (int jj = 0; jj < 8; ++jj)
            d[jj] = f2bf(src[(size_t)jj * 3136]);
        *(u16x8*)(xpad + ((((size_t)n * 58 + h + 1) * 16 + cs) * 58 + (w + 1)) * 8) = d;
    }
}

// ---------------- implicit-GEMM conv, double-buffered + counted vmcnt ----------------
// Block: 64 o x (8 rows x 56), 4 waves each 64o x 112s. Chunk = 32 c.
// LDS xs: [cseg_rel 0..3][pos 0..639 (580 used)] 16B ; wl: [cseg_rel][kk][o 0..63] 16B.
__global__ __launch_bounds__(256) void conv4_k(const unsigned short* __restrict__ xpad,
                                               const unsigned short* __restrict__ wq,
                                               float* __restrict__ out) {
    __shared__ __align__(16) unsigned short xs[2][2560 * 8];   // 2 x 40960 B
    __shared__ __align__(16) unsigned short wl[2][2304 * 8];   // 2 x 36864 B

    const int tid = threadIdx.x;
    const int h0 = blockIdx.x * 8;
    const int n = blockIdx.y;
    const int o0 = blockIdx.z * 64;
    const int lane = tid & 63;
    const int wave = tid >> 6;
    const int l16 = lane & 15;
    const int kgrp = lane >> 4;

    // ---- staging source offsets (c0-independent base) ----
    int offx[10];
#pragma unroll
    for (int i = 0; i < 10; ++i) {
        int ci = i * 256 + tid;          // 0..2559
        int cs = ci / 640;               // relative cseg 0..3
        int pos = ci - cs * 640;
        int pe = pos < 580 ? pos : 579;
        int r = pe / 58;
        int col = pe - r * 58;
        offx[i] = (((n * 58 + h0 + r) * 16 + cs) * 58 + col) * 8;
    }
    int offw[9];
#pragma unroll
    for (int i = 0; i < 9; ++i) {
        int ci = i * 256 + tid;          // 0..2303
        int cs = ci / 576;
        int rem = ci - cs * 576;
        int kk = rem >> 6;
        int o = rem & 63;
        offw[i] = ((kk * 16 + cs) * 256 + o0 + o) * 8;
    }

    // ---- MFMA fragment bases ----
    int rr[7], wwv[7], bb[7];
#pragma unroll
    for (int f = 0; f < 7; ++f) {
        int s = wave * 112 + f * 16 + l16;   // 0..447
        int r = s / 56;
        int w = s - r * 56;
        rr[f] = r; wwv[f] = w;
        bb[f] = (kgrp * 640 + r * 58 + w) * 8;
    }
    const int ab = (kgrp * 576 + l16) * 8;

    f32x4 acc[4][7];
#pragma unroll
    for (int a = 0; a < 4; ++a)
#pragma unroll
        for (int f = 0; f < 7; ++f) acc[a][f] = (f32x4){0.f, 0.f, 0.f, 0.f};

    const int ldst = wave * 64 * 8;      // wave-uniform LDS dest stride unit

    // ---- prologue: stage chunk 0 into buf 0 ----
#pragma unroll
    for (int i = 0; i < 10; ++i)
        gload16(xpad + offx[i], &xs[0][i * 2048 + ldst]);
#pragma unroll
    for (int i = 0; i < 9; ++i)
        gload16(wq + offw[i], &wl[0][i * 2048 + ldst]);

#pragma unroll
    for (int t = 0; t < 4; ++t) {
        const int cur = t & 1;
        if (t < 3) {
            const int c0 = (t + 1) * 32;
            // x term: (c0/8)*58*8 = c0*58 ; w term: (c0/8)*256*8 = c0*256
#pragma unroll
            for (int i = 0; i < 10; ++i)
                gload16(xpad + offx[i] + c0 * 58, &xs[cur ^ 1][i * 2048 + ldst]);
#pragma unroll
            for (int i = 0; i < 9; ++i)
                gload16(wq + offw[i] + c0 * 256, &wl[cur ^ 1][i * 2048 + ldst]);
            asm volatile("s_waitcnt vmcnt(19)" ::: "memory");
        } else {
            asm volatile("s_waitcnt vmcnt(0)" ::: "memory");
        }
        __builtin_amdgcn_s_barrier();
        asm volatile("" ::: "memory");

        const unsigned short* xsb = xs[cur];
        const unsigned short* wlb = wl[cur];
#pragma unroll
        for (int kk = 0; kk < 9; ++kk) {
            const int kh = kk / 3;
            const int kw = kk - kh * 3;
            s16x8 a0 = ldfrag(wlb + ab + kk * 512);
            s16x8 a1 = ldfrag(wlb + ab + kk * 512 + 128);
            s16x8 a2 = ldfrag(wlb + ab + kk * 512 + 256);
            s16x8 a3 = ldfrag(wlb + ab + kk * 512 + 384);
            const int xo = (kh * 58 + kw) * 8;
#pragma unroll
            for (int f = 0; f < 7; ++f) {
                s16x8 b = ldfrag(xsb + bb[f] + xo);
                acc[0][f] = __builtin_amdgcn_mfma_f32_16x16x32_bf16(a0, b, acc[0][f], 0, 0, 0);
                acc[1][f] = __builtin_amdgcn_mfma_f32_16x16x32_bf16(a1, b, acc[1][f], 0, 0, 0);
                acc[2][f] = __builtin_amdgcn_mfma_f32_16x16x32_bf16(a2, b, acc[2][f], 0, 0, 0);
                acc[3][f] = __builtin_amdgcn_mfma_f32_16x16x32_bf16(a3, b, acc[3][f], 0, 0, 0);
            }
        }
        __builtin_amdgcn_s_barrier();
        asm volatile("" ::: "memory");
    }

    // ---- epilogue (mapping verified rounds 1-3) ----
#pragma unroll
    for (int of = 0; of < 4; ++of) {
        int ob = o0 + of * 16 + kgrp * 4;
#pragma unroll
        for (int f = 0; f < 7; ++f) {
            int h = h0 + rr[f];
            float* dst = out + ((size_t)(n * 256 + ob) * 56 + h) * 56 + wwv[f];
#pragma unroll
            for (int j = 0; j < 4; ++j) dst[(size_t)j * 3136] = acc[of][f][j];
        }
    }
}

extern "C" void kernel_launch(void* const* d_in, const int* in_sizes, int n_in,
                              void* d_out, int out_size, void* d_ws, size_t ws_size,
                              hipStream_t stream) {
    const float* x = (const float*)d_in[0];
    const float* pc = (const float*)d_in[1];
    const float* ql = (const float*)d_in[2];
    float* out = (float*)d_out;

    unsigned short* xpad = (unsigned short*)d_ws;
    unsigned short* wq = (unsigned short*)((char*)d_ws + XPAD_BYTES);

    border_k<<<456, 256, 0, stream>>>(xpad);
    quant_k<<<1152, 256, 0, stream>>>(pc, ql, wq);
    xform_k<<<dim3(56, 32), 256, 0, stream>>>(x, xpad);
    conv4_k<<<dim3(7, 32, 4), 256, 0, stream>>>(xpad, wq, out);
}

// Round 5
// 94.093 us; speedup vs baseline: 1.6754x; 1.2264x over previous
//
#include <hip/hip_runtime.h>
#include <stdint.h>

typedef short s16x8 __attribute__((ext_vector_type(8)));
typedef unsigned short u16x8 __attribute__((ext_vector_type(8)));
typedef float f32x4 __attribute__((ext_vector_type(4)));

#define XPAD_BYTES ((size_t)(32 * 58 * 58 * 128) * 2)

// xpad layout: [n][row 0..57][cseg 0..15][col 0..57][8c]  (16B chunk = 8 c's)
// wq   layout: [kk 0..8][cseg 0..15][o 0..255][8c]

static __device__ __forceinline__ unsigned short f2bf(float f) {
    union { float f; uint32_t u; } v; v.f = f;
    uint32_t r = v.u + 0x7FFFu + ((v.u >> 16) & 1u);
    return (unsigned short)(r >> 16);
}

static __device__ __forceinline__ s16x8 ldfrag(const unsigned short* p) {
    return *(const s16x8*)p;
}

static __device__ __forceinline__ void gload16(const unsigned short* g, unsigned short* l) {
    __builtin_amdgcn_global_load_lds(
        (const __attribute__((address_space(1))) uint32_t*)g,
        (__attribute__((address_space(3))) uint32_t*)l, 16, 0, 0);
}

// ---------------- weight quantization -> [kk][cseg][o][8] ----------------
__global__ void quant_k(const float* __restrict__ pc,
                        const float* __restrict__ ql,
                        unsigned short* __restrict__ wq) {
    int p = blockIdx.x * 256 + threadIdx.x;
    if (p >= 9 * 16 * 256 * 8) return;
    int j = p & 7;
    int o = (p >> 3) & 255;
    int cs = (p >> 11) & 15;
    int kk = p >> 15;
    int c = cs * 8 + j;
    const float* v = pc + ((size_t)((o * 128 + c) * 9 + kk) * 7);
    float vv[7];
    float s = 0.f;
#pragma unroll
    for (int l = 0; l < 7; ++l) { vv[l] = v[l]; s += vv[l] * vv[l]; }
    float norm = sqrtf(s);
    float best = 10.0f * (vv[0] / norm);
    int bi = 0;
#pragma unroll
    for (int l = 1; l < 7; ++l) {
        float t = 10.0f * (vv[l] / norm);
        if (t > best) { best = t; bi = l; }
    }
    wq[p] = f2bf(ql[bi]);
}

// ---------------- zero the halo border of xpad ----------------
__global__ void border_k(unsigned short* __restrict__ xpad) {
    int i = blockIdx.x * 256 + threadIdx.x;   // 456*256 = 116736 = 32*3648
    const u16x8 z = (u16x8){0, 0, 0, 0, 0, 0, 0, 0};
    int n = i / 3648;
    int rem = i - n * 3648;
    int r, cs, col;
    if (rem < 1856) {
        int rt = rem / 928;
        int q = rem - rt * 928;
        r = rt * 57;
        cs = q / 58;
        col = q - cs * 58;
    } else {
        int rem2 = rem - 1856;
        int ct = rem2 / 896;
        int q = rem2 - ct * 896;
        col = ct * 57;
        cs = q / 56;
        r = 1 + (q - cs * 56);
    }
    *(u16x8*)(xpad + ((((size_t)n * 58 + r) * 16 + cs) * 58 + col) * 8) = z;
}

// ---------------- x: NCHW f32 -> padded [n][row][cseg][col][8] bf16 ----------------
__global__ __launch_bounds__(256) void xform_k(const float* __restrict__ x,
                                               unsigned short* __restrict__ xpad) {
    const int h = blockIdx.x;
    const int n = blockIdx.y;
    const int t = threadIdx.x;
    if (t >= 224) return;
    int cgrp = t / 56;
    int w = t - cgrp * 56;
#pragma unroll
    for (int seg = 0; seg < 4; ++seg) {
        int cs = seg * 4 + cgrp;
        const float* src = x + ((size_t)(n * 128 + cs * 8) * 56 + h) * 56 + w;
        u16x8 d;
#pragma unroll
        for (int jj = 0; jj < 8; ++jj)
            d[jj] = f2bf(src[(size_t)jj * 3136]);
        *(u16x8*)(xpad + ((((size_t)n * 58 + h + 1) * 16 + cs) * 58 + (w + 1)) * 8) = d;
    }
}

// ---------------- implicit-GEMM conv: x in LDS (dbuf), weights global->reg ----------------
// Block: 64 o x (8 rows x 56) = 448 spatial, 4 waves each 64o x 112s. Chunk = 32 c.
// LDS xs[buf]: [cseg_rel 0..3][pos = r*58+col, 580] 16B chunks (37120 B per buf).
__global__ __launch_bounds__(256, 2) void conv5_k(const unsigned short* __restrict__ xpad,
                                                  const unsigned short* __restrict__ wq,
                                                  float* __restrict__ out) {
    __shared__ __align__(16) unsigned short xs[2][2320 * 8];   // 74240 B total

    const int tid = threadIdx.x;
    const int h0 = blockIdx.x * 8;
    const int n = blockIdx.y;
    const int o0 = blockIdx.z * 64;
    const int lane = tid & 63;
    const int wave = tid >> 6;
    const int l16 = lane & 15;
    const int kgrp = lane >> 4;

    // ---- x staging source offsets (chunk-0 base; chunk t adds t*1856 elems) ----
    int offx[10];
    bool v9;
    {
#pragma unroll
        for (int i = 0; i < 10; ++i) {
            int ci = i * 256 + tid;          // 0..2559
            bool valid = ci < 2320;
            int ce = valid ? ci : 0;
            int cs = ce / 580;               // relative cseg 0..3
            int pos = ce - cs * 580;
            int r = pos / 58;
            int col = pos - r * 58;
            offx[i] = (((n * 58 + h0 + r) * 16 + cs) * 58 + col) * 8;
            if (i == 9) v9 = valid;
        }
    }

    // ---- B-fragment LDS bases ----
    int bb[7];
#pragma unroll
    for (int f = 0; f < 7; ++f) {
        int s = wave * 112 + f * 16 + l16;   // 0..447
        int r = s / 56;
        int w = s - r * 56;
        bb[f] = (kgrp * 580 + r * 58 + w) * 8;
    }

    // ---- A-fragment global base: A(kk,t,of) = wA + kk*32768 + t*8192 + of*128 ----
    const unsigned short* wA = wq + (size_t)(kgrp * 256 + o0 + l16) * 8;

    f32x4 acc[4][7];
#pragma unroll
    for (int a = 0; a < 4; ++a)
#pragma unroll
        for (int f = 0; f < 7; ++f) acc[a][f] = (f32x4){0.f, 0.f, 0.f, 0.f};

    // ---- prologue: stage chunk 0 into buf 0 ----
#pragma unroll
    for (int i = 0; i < 9; ++i)
        gload16(xpad + offx[i], &xs[0][(i * 256 + wave * 64) * 8]);
    if (v9)
        gload16(xpad + offx[9], &xs[0][(2304 + wave * 64) * 8]);
    __syncthreads();

#pragma unroll
    for (int t = 0; t < 4; ++t) {
        const int cur = t & 1;
        if (t < 3) {
            const int xoff = (t + 1) * 1856;
#pragma unroll
            for (int i = 0; i < 9; ++i)
                gload16(xpad + offx[i] + xoff, &xs[cur ^ 1][(i * 256 + wave * 64) * 8]);
            if (v9)
                gload16(xpad + offx[9] + xoff, &xs[cur ^ 1][(2304 + wave * 64) * 8]);
        }

        const unsigned short* xsb = xs[cur];

        s16x8 A0[4], A1[4];
#pragma unroll
        for (int of = 0; of < 4; ++of)
            A0[of] = ldfrag(wA + t * 8192 + of * 128);

#pragma unroll
        for (int kk = 0; kk < 9; ++kk) {
            s16x8 Ac[4];
#pragma unroll
            for (int of = 0; of < 4; ++of) Ac[of] = (kk & 1) ? A1[of] : A0[of];
            if (kk < 8) {
#pragma unroll
                for (int of = 0; of < 4; ++of) {
                    s16x8 vld = ldfrag(wA + (kk + 1) * 32768 + t * 8192 + of * 128);
                    if (kk & 1) A0[of] = vld; else A1[of] = vld;
                }
            }
            const int kh = kk / 3;
            const int kw = kk - kh * 3;
            const int xo = (kh * 58 + kw) * 8;
#pragma unroll
            for (int f = 0; f < 7; ++f) {
                s16x8 b = ldfrag(xsb + bb[f] + xo);
                acc[0][f] = __builtin_amdgcn_mfma_f32_16x16x32_bf16(Ac[0], b, acc[0][f], 0, 0, 0);
                acc[1][f] = __builtin_amdgcn_mfma_f32_16x16x32_bf16(Ac[1], b, acc[1][f], 0, 0, 0);
                acc[2][f] = __builtin_amdgcn_mfma_f32_16x16x32_bf16(Ac[2], b, acc[2][f], 0, 0, 0);
                acc[3][f] = __builtin_amdgcn_mfma_f32_16x16x32_bf16(Ac[3], b, acc[3][f], 0, 0, 0);
            }
        }
        __syncthreads();
    }

    // ---- epilogue (mapping verified rounds 1-4) ----
#pragma unroll
    for (int of = 0; of < 4; ++of) {
        int ob = o0 + of * 16 + kgrp * 4;
#pragma unroll
        for (int f = 0; f < 7; ++f) {
            int s = wave * 112 + f * 16 + l16;
            int r = s / 56;
            int w = s - r * 56;
            int h = h0 + r;
            float* dst = out + ((size_t)(n * 256 + ob) * 56 + h) * 56 + w;
#pragma unroll
            for (int j = 0; j < 4; ++j) dst[(size_t)j * 3136] = acc[of][f][j];
        }
    }
}

extern "C" void kernel_launch(void* const* d_in, const int* in_sizes, int n_in,
                              void* d_out, int out_size, void* d_ws, size_t ws_size,
                              hipStream_t stream) {
    const float* x = (const float*)d_in[0];
    const float* pc = (const float*)d_in[1];
    const float* ql = (const float*)d_in[2];
    float* out = (float*)d_out;

    unsigned short* xpad = (unsigned short*)d_ws;
    unsigned short* wq = (unsigned short*)((char*)d_ws + XPAD_BYTES);

    border_k<<<456, 256, 0, stream>>>(xpad);
    quant_k<<<1152, 256, 0, stream>>>(pc, ql, wq);
    xform_k<<<dim3(56, 32), 256, 0, stream>>>(x, xpad);
    conv5_k<<<dim3(7, 32, 4), 256, 0, stream>>>(xpad, wq, out);
}